// Round 1
// baseline (97.007 us; speedup 1.0000x reference)
//
#include <hip/hip_runtime.h>
#include <hip/hip_bf16.h>

typedef __attribute__((ext_vector_type(8))) short short8;
typedef __attribute__((ext_vector_type(4))) float f32x4;

#define NFACE 16384
#define NBATCH 8
#define CIN 128
#define COUT 128
#define KGEMM 512
#define MBLK 64
#define LDF 520  // fcv LDS row stride in bf16 elems: 512 + 8 (16B pad -> stride 1040B)

__device__ __forceinline__ unsigned short f2bf(float x) {
    union { float f; unsigned u; } v; v.f = x;
    unsigned r = v.u + 0x7fffu + ((v.u >> 16) & 1u);  // RNE
    return (unsigned short)(r >> 16);
}

// weight (OUT_C, C, 1, 4) fp32  ->  Bt[o][kk*128 + c] bf16
__global__ void wconv_kernel(const float* __restrict__ w, unsigned short* __restrict__ bt) {
    int i = blockIdx.x * 256 + threadIdx.x;
    if (i >= COUT * CIN) return;
    int o = i >> 7, c = i & 127;
#pragma unroll
    for (int kk = 0; kk < 4; ++kk)
        bt[o * KGEMM + kk * CIN + c] = f2bf(w[(o * CIN + c) * 4 + kk]);
}

__global__ __launch_bounds__(256, 2)
void meshconv_kernel(const float* __restrict__ feat,
                     const int* __restrict__ ring,
                     const unsigned short* __restrict__ wbt,
                     const float* __restrict__ bias,
                     float* __restrict__ out)
{
    __shared__ unsigned short fcv[MBLK * LDF];
    __shared__ int ridx[MBLK * 6];

    const int t = threadIdx.x;
    const int base = blockIdx.x * MBLK;  // global face id (blocks never straddle a batch: 16384 % 64 == 0)
    const int batch = base >> 14;        // / 16384
    const float* __restrict__ fb = feat + (size_t)batch * NFACE * CIN;

    for (int i = t; i < MBLK * 6; i += 256)
        ridx[i] = ring[(size_t)base * 6 + i];
    __syncthreads();

    // ---- phase 1: build fcv tile (64 faces x [4 x 128]) in LDS as bf16 ----
    {
        const int c = t & 127;
        const int fhalf = t >> 7;  // 2 faces per iteration
        for (int it = 0; it < MBLK / 2; ++it) {
            const int fl = it * 2 + fhalf;
            const int* ri = &ridx[fl * 6];
            float n0 = fb[(size_t)ri[0] * CIN + c];
            float n1 = fb[(size_t)ri[1] * CIN + c];
            float n2 = fb[(size_t)ri[2] * CIN + c];
            float n3 = fb[(size_t)ri[3] * CIN + c];
            float n4 = fb[(size_t)ri[4] * CIN + c];
            float n5 = fb[(size_t)ri[5] * CIN + c];

            float fc1 = n1 + n2 + n3 + n4 + n5;
            float fc2 = fabsf(5.0f * n0 - fc1);
            float fc3 = fabsf(n1 - n2) + fabsf(n1 - n3) + fabsf(n1 - n4) + fabsf(n1 - n5)
                      + fabsf(n2 - n3) + fabsf(n2 - n4) + fabsf(n2 - n5)
                      + fabsf(n3 - n4) + fabsf(n3 - n5)
                      + fabsf(n4 - n5);

            unsigned short* row = &fcv[fl * LDF];
            row[c]           = f2bf(n0);
            row[128 + c]     = f2bf(fc1);
            row[256 + c]     = f2bf(fc2);
            row[384 + c]     = f2bf(fc3);
        }
    }
    __syncthreads();

    // ---- phase 2: MFMA GEMM  [64 x 512] x [512 x 128] ----
    const int w  = t >> 6;   // wave 0..3 -> cols [32w, 32w+32)
    const int l  = t & 63;
    const int lo = l & 15;
    const int hi = l >> 4;
    const int col0 = w * 32;

    f32x4 acc[4][2];
#pragma unroll
    for (int rt = 0; rt < 4; ++rt)
#pragma unroll
        for (int ct = 0; ct < 2; ++ct)
            acc[rt][ct] = (f32x4){0.f, 0.f, 0.f, 0.f};

    const unsigned short* __restrict__ wb0 = wbt + (size_t)(col0 + lo) * KGEMM;

    for (int ks = 0; ks < 16; ++ks) {
        const int k0 = ks * 32 + hi * 8;
        short8 a0 = *(const short8*)&fcv[(0 * 16 + lo) * LDF + k0];
        short8 a1 = *(const short8*)&fcv[(1 * 16 + lo) * LDF + k0];
        short8 a2 = *(const short8*)&fcv[(2 * 16 + lo) * LDF + k0];
        short8 a3 = *(const short8*)&fcv[(3 * 16 + lo) * LDF + k0];
        short8 b0 = *(const short8*)&wb0[k0];
        short8 b1 = *(const short8*)&wb0[16 * KGEMM + k0];

        acc[0][0] = __builtin_amdgcn_mfma_f32_16x16x32_bf16(a0, b0, acc[0][0], 0, 0, 0);
        acc[1][0] = __builtin_amdgcn_mfma_f32_16x16x32_bf16(a1, b0, acc[1][0], 0, 0, 0);
        acc[2][0] = __builtin_amdgcn_mfma_f32_16x16x32_bf16(a2, b0, acc[2][0], 0, 0, 0);
        acc[3][0] = __builtin_amdgcn_mfma_f32_16x16x32_bf16(a3, b0, acc[3][0], 0, 0, 0);
        acc[0][1] = __builtin_amdgcn_mfma_f32_16x16x32_bf16(a0, b1, acc[0][1], 0, 0, 0);
        acc[1][1] = __builtin_amdgcn_mfma_f32_16x16x32_bf16(a1, b1, acc[1][1], 0, 0, 0);
        acc[2][1] = __builtin_amdgcn_mfma_f32_16x16x32_bf16(a2, b1, acc[2][1], 0, 0, 0);
        acc[3][1] = __builtin_amdgcn_mfma_f32_16x16x32_bf16(a3, b1, acc[3][1], 0, 0, 0);
    }

    // ---- epilogue: + bias, store fp32 ----
    const float bo0 = bias[col0 + lo];
    const float bo1 = bias[col0 + 16 + lo];
#pragma unroll
    for (int rt = 0; rt < 4; ++rt) {
#pragma unroll
        for (int v = 0; v < 4; ++v) {
            const int r = base + rt * 16 + hi * 4 + v;  // C/D: row=(l>>4)*4+v, col=l&15  [m89]
            out[(size_t)r * COUT + col0 + lo]      = acc[rt][0][v] + bo0;
            out[(size_t)r * COUT + col0 + 16 + lo] = acc[rt][1][v] + bo1;
        }
    }
}

__global__ void zero_kernel(const int* __restrict__ zm, const int* __restrict__ zf,
                            float* __restrict__ out) {
    const int i = blockIdx.x;
    const size_t face = (size_t)zm[i] * NFACE + zf[i];
    out[face * COUT + threadIdx.x] = 0.0f;
}

extern "C" void kernel_launch(void* const* d_in, const int* in_sizes, int n_in,
                              void* d_out, int out_size, void* d_ws, size_t ws_size,
                              hipStream_t stream) {
    const float* feat = (const float*)d_in[0];
    const int*   ring = (const int*)d_in[1];
    const float* wgt  = (const float*)d_in[2];
    const float* bias = (const float*)d_in[3];
    const int*   zm   = (const int*)d_in[4];
    const int*   zf   = (const int*)d_in[5];
    float* out = (float*)d_out;
    unsigned short* wbt = (unsigned short*)d_ws;  // 128*512*2 = 128 KiB

    hipLaunchKernelGGL(wconv_kernel, dim3((COUT * CIN + 255) / 256), dim3(256), 0, stream,
                       wgt, wbt);
    hipLaunchKernelGGL(meshconv_kernel, dim3((NBATCH * NFACE) / MBLK), dim3(256), 0, stream,
                       feat, ring, wbt, bias, out);
    hipLaunchKernelGGL(zero_kernel, dim3(1024), dim3(128), 0, stream, zm, zf, out);
}